// Round 1
// baseline (336.030 us; speedup 1.0000x reference)
//
#include <hip/hip_runtime.h>

#define RED_THREADS 512

// Persistent-wave SDF kernel.
// One 64-lane wave processes a strided sequence of ~25 points (grid-stride by
// totalWaves). Lane k<60 owns neighbor k of the current point and loads its 7
// scalars (v.xyz, vn.xyz, sr) directly from global — a wave's 7 dword loads
// cover the same contiguous 720/240-B rows as the old float4+LDS staging, so
// line utilization is identical, but there is no LDS round-trip, no
// __syncthreads, and no per-point block launch.
// Depth-2 software pipeline: loads for point i+1 are issued before the compute
// of point i consumes its (previous-iteration) loads, so the compiler emits a
// counted s_waitcnt vmcnt(N) and memory latency hides under compute + other
// waves. sdf^2 accumulates in registers; 2 atomics per wave at the end.
__global__ __launch_bounds__(256) void sdf_main(
    const float* __restrict__ points,
    const float* __restrict__ v,
    const float* __restrict__ vn,
    const float* __restrict__ sr,
    float* __restrict__ ws,
    int NP, int P, int totalWaves, int slots, int slotStride)
{
    constexpr int K = 60;
    const int lane = threadIdx.x & 63;
    const int wid  = blockIdx.x * 4 + (threadIdx.x >> 6);
    const bool lk  = lane < K;

    const int stride   = totalWaves;
    const size_t vstep = (size_t)stride * (K * 3);
    const size_t sstep = (size_t)stride * K;
    const size_t pstep = (size_t)stride * 3;

    int pt = wid;
    bool have = pt < NP;

    const float* vp = v      + (size_t)pt * (K * 3) + 3 * lane;
    const float* qp = vn     + (size_t)pt * (K * 3) + 3 * lane;
    const float* sp = sr     + (size_t)pt * K       + lane;
    const float* pp = points + (size_t)pt * 3;

    // current-point registers (lanes >= K keep the benign init values)
    float cvx = 0.f, cvy = 0.f, cvz = 0.f;
    float cnx = 0.f, cny = 0.f, cnz = 0.f, cs = 1.f;
    float cpx = 0.f, cpy = 0.f, cpz = 0.f;
    if (have) {
        if (lk) {
            cvx = vp[0]; cvy = vp[1]; cvz = vp[2];
            cnx = qp[0]; cny = qp[1]; cnz = qp[2];
            cs  = sp[0];
        }
        cpx = pp[0]; cpy = pp[1]; cpz = pp[2];
    }

    float acc0 = 0.f, acc1 = 0.f;

    while (have) {
        const bool haveN = (pt + stride) < NP;
        // issue next-point loads FIRST (stay in flight across the compute)
        float nvx = 0.f, nvy = 0.f, nvz = 0.f;
        float nnx = 0.f, nny = 0.f, nnz = 0.f, ns = 1.f;
        float npx = 0.f, npy = 0.f, npz = 0.f;
        if (haveN) {
            if (lk) {
                nvx = vp[vstep + 0]; nvy = vp[vstep + 1]; nvz = vp[vstep + 2];
                nnx = qp[vstep + 0]; nny = qp[vstep + 1]; nnz = qp[vstep + 2];
                ns  = sp[sstep];
            }
            npx = pp[pstep + 0]; npy = pp[pstep + 1]; npz = pp[pstep + 2];
        }

        // compute current point (loads were issued one iteration ago)
        const float dx = cpx - cvx;
        const float dy = cpy - cvy;
        const float dz = cpz - cvz;
        const float d2 = dx * dx + dy * dy + dz * dz;
        const float wq = 1.0f - d2 / cs;
        const float w2 = wq * wq;
        const float phi = (d2 < cs) ? (w2 * w2) : 1e-18f;
        const float dot = cnx * dx + cny * dy + cnz * dz;
        float num = lk ? (phi * dot) : 0.f;
        float den = lk ? phi : 0.f;
        #pragma unroll
        for (int off = 32; off >= 1; off >>= 1) {
            num += __shfl_xor(num, off, 64);
            den += __shfl_xor(den, off, 64);
        }
        const float sdf = num / den;
        const float s2  = sdf * sdf;
        if (pt < P) acc0 += s2; else acc1 += s2;   // pt is wave-uniform

        // rotate pipeline registers
        cvx = nvx; cvy = nvy; cvz = nvz;
        cnx = nnx; cny = nny; cnz = nnz; cs = ns;
        cpx = npx; cpy = npy; cpz = npz;
        vp += vstep; qp += vstep; sp += sstep; pp += pstep;
        pt += stride; have = haveN;
    }

    if (lane == 0) {
        const int slot = wid & (slots - 1);
        atomicAdd(&ws[slot * slotStride + 0], acc0);
        atomicAdd(&ws[slot * slotStride + 1], acc1);
    }
}

// Single-block final reduction over `slots` partial sums per batch index.
__global__ __launch_bounds__(RED_THREADS) void sdf_reduce(
    const float* __restrict__ ws, float* __restrict__ out,
    int N, int slots, int slotStride)
{
    __shared__ float sm0[RED_THREADS];
    __shared__ float sm1[RED_THREADS];
    const int tid = threadIdx.x;
    float a = 0.f, b = 0.f;
    for (int s = tid; s < slots; s += RED_THREADS) {
        a += ws[s * slotStride + 0];
        if (N > 1) b += ws[s * slotStride + 1];
    }
    sm0[tid] = a;
    sm1[tid] = b;
    __syncthreads();
    #pragma unroll
    for (int s = RED_THREADS / 2; s >= 1; s >>= 1) {
        if (tid < s) {
            sm0[tid] += sm0[tid + s];
            sm1[tid] += sm1[tid + s];
        }
        __syncthreads();
    }
    if (tid == 0) {
        out[0] = sm0[0];
        if (N > 1) out[1] = sm1[0];
    }
}

extern "C" void kernel_launch(void* const* d_in, const int* in_sizes, int n_in,
                              void* d_out, int out_size, void* d_ws, size_t ws_size,
                              hipStream_t stream) {
    const float* points = (const float*)d_in[0];
    const float* v      = (const float*)d_in[1];
    const float* vn     = (const float*)d_in[2];
    const float* sr     = (const float*)d_in[3];
    float* out = (float*)d_out;
    float* ws  = (float*)d_ws;

    const int NP = in_sizes[0] / 3;        // N*P total points (200000)
    const int N  = out_size;               // 2
    const int P  = NP / N;                 // 100000

    // Atomic-scatter geometry: one 64-B line per slot when workspace allows.
    int slots = 512, slotStride = 16;      // 32 KiB
    if (ws_size < (size_t)(slots * slotStride * sizeof(float))) {
        slots = 256; slotStride = 2;       // 2 KiB fallback
    }

    hipMemsetAsync(ws, 0, (size_t)slots * slotStride * sizeof(float), stream);

    // Persistent grid: 2048 blocks x 4 waves = 8192 waves (8 blocks/CU target),
    // each wave grid-strides over ~NP/8192 points.
    int blocks = (NP + 3) / 4;
    if (blocks > 2048) blocks = 2048;
    const int totalWaves = blocks * 4;

    sdf_main<<<blocks, 256, 0, stream>>>(points, v, vn, sr, ws, NP, P,
                                         totalWaves, slots, slotStride);
    sdf_reduce<<<1, RED_THREADS, 0, stream>>>(ws, out, N, slots, slotStride);
}

// Round 2
// 330.633 us; speedup vs baseline: 1.0163x; 1.0163x over previous
//
#include <hip/hip_runtime.h>

#define RED_THREADS 512

// Pipeline-stage register set for one point: the 7 per-lane neighbor scalars
// plus the wave-uniform point coords.
struct PtData {
    float vx, vy, vz, nx, ny, nz, s, px, py, pz;
};

// Issue all loads for one point. v is read non-temporally: it is a 144-MB
// stream with zero intra-dispatch reuse; keeping it OUT of L3 lets the
// vn+sr+points set (~194 MB) stay resident across dispatches (L3 = 256 MB).
__device__ __forceinline__ PtData load_pt(
    const float* __restrict__ vp, const float* __restrict__ qp,
    const float* __restrict__ sp, const float* __restrict__ pp,
    bool lk, bool valid)
{
    PtData r;
    r.vx = r.vy = r.vz = 0.f;
    r.nx = r.ny = r.nz = 0.f;
    r.s  = 1.f;
    r.px = r.py = r.pz = 0.f;
    if (valid) {
        if (lk) {
            r.vx = __builtin_nontemporal_load(vp + 0);
            r.vy = __builtin_nontemporal_load(vp + 1);
            r.vz = __builtin_nontemporal_load(vp + 2);
            r.nx = qp[0]; r.ny = qp[1]; r.nz = qp[2];
            r.s  = sp[0];
        }
        r.px = pp[0]; r.py = pp[1]; r.pz = pp[2];
    }
    return r;
}

// Persistent-wave SDF kernel, depth-3 software pipeline.
// One wave per point; lane k<60 owns neighbor k. Stages A (ready), B (one
// iteration out), C (two iterations out) keep 14 loads / ~3.4 KB in flight
// per wave at the compute point, so the compiler emits a counted
// s_waitcnt vmcnt(14) and queued memory latency is covered by two full
// iterations of compute across 32 waves/CU.
__global__ __launch_bounds__(256) void sdf_main(
    const float* __restrict__ points,
    const float* __restrict__ v,
    const float* __restrict__ vn,
    const float* __restrict__ sr,
    float* __restrict__ ws,
    int NP, int P, int totalWaves, int slots, int slotStride)
{
    constexpr int K = 60;
    const int lane = threadIdx.x & 63;
    const int wid  = blockIdx.x * 4 + (threadIdx.x >> 6);
    const bool lk  = lane < K;

    const int stride   = totalWaves;
    const size_t vstep = (size_t)stride * (K * 3);
    const size_t sstep = (size_t)stride * K;
    const size_t pstep = (size_t)stride * 3;

    int pt = wid;

    const float* vp = v      + (size_t)pt * (K * 3) + 3 * lane;
    const float* qp = vn     + (size_t)pt * (K * 3) + 3 * lane;
    const float* sp = sr     + (size_t)pt * K       + lane;
    const float* pp = points + (size_t)pt * 3;

    // Prologue: fill stages A and B.
    PtData A = load_pt(vp, qp, sp, pp, lk, pt < NP);
    PtData B = load_pt(vp + vstep, qp + vstep, sp + sstep, pp + pstep,
                       lk, pt + stride < NP);
    // Pointers now track stage C (= pt + 2*stride).
    vp += 2 * vstep; qp += 2 * vstep; sp += 2 * sstep; pp += 2 * pstep;

    float acc0 = 0.f, acc1 = 0.f;

    while (pt < NP) {
        // Issue stage-C loads first; they stay in flight across the compute
        // and reduction below plus the whole next iteration.
        PtData C = load_pt(vp, qp, sp, pp, lk, pt + 2 * stride < NP);

        // Compute on stage A (loads issued two iterations ago).
        const float dx = A.px - A.vx;
        const float dy = A.py - A.vy;
        const float dz = A.pz - A.vz;
        const float d2 = dx * dx + dy * dy + dz * dz;
        const float wq = 1.0f - d2 / A.s;
        const float w2 = wq * wq;
        const float phi = (d2 < A.s) ? (w2 * w2) : 1e-18f;
        const float dot = A.nx * dx + A.ny * dy + A.nz * dz;
        float num = lk ? (phi * dot) : 0.f;
        float den = lk ? phi : 0.f;
        #pragma unroll
        for (int off = 32; off >= 1; off >>= 1) {
            num += __shfl_xor(num, off, 64);
            den += __shfl_xor(den, off, 64);
        }
        const float sdf = num / den;
        const float s2  = sdf * sdf;
        if (pt < P) acc0 += s2; else acc1 += s2;   // pt is wave-uniform

        // Rotate pipeline.
        A = B; B = C;
        vp += vstep; qp += vstep; sp += sstep; pp += pstep;
        pt += stride;
    }

    if (lane == 0) {
        const int slot = wid & (slots - 1);
        atomicAdd(&ws[slot * slotStride + 0], acc0);
        atomicAdd(&ws[slot * slotStride + 1], acc1);
    }
}

// Single-block final reduction over `slots` partial sums per batch index.
__global__ __launch_bounds__(RED_THREADS) void sdf_reduce(
    const float* __restrict__ ws, float* __restrict__ out,
    int N, int slots, int slotStride)
{
    __shared__ float sm0[RED_THREADS];
    __shared__ float sm1[RED_THREADS];
    const int tid = threadIdx.x;
    float a = 0.f, b = 0.f;
    for (int s = tid; s < slots; s += RED_THREADS) {
        a += ws[s * slotStride + 0];
        if (N > 1) b += ws[s * slotStride + 1];
    }
    sm0[tid] = a;
    sm1[tid] = b;
    __syncthreads();
    #pragma unroll
    for (int s = RED_THREADS / 2; s >= 1; s >>= 1) {
        if (tid < s) {
            sm0[tid] += sm0[tid + s];
            sm1[tid] += sm1[tid + s];
        }
        __syncthreads();
    }
    if (tid == 0) {
        out[0] = sm0[0];
        if (N > 1) out[1] = sm1[0];
    }
}

extern "C" void kernel_launch(void* const* d_in, const int* in_sizes, int n_in,
                              void* d_out, int out_size, void* d_ws, size_t ws_size,
                              hipStream_t stream) {
    const float* points = (const float*)d_in[0];
    const float* v      = (const float*)d_in[1];
    const float* vn     = (const float*)d_in[2];
    const float* sr     = (const float*)d_in[3];
    float* out = (float*)d_out;
    float* ws  = (float*)d_ws;

    const int NP = in_sizes[0] / 3;        // N*P total points (200000)
    const int N  = out_size;               // 2
    const int P  = NP / N;                 // 100000

    // Atomic-scatter geometry: one 64-B line per slot when workspace allows.
    int slots = 512, slotStride = 16;      // 32 KiB
    if (ws_size < (size_t)(slots * slotStride * sizeof(float))) {
        slots = 256; slotStride = 2;       // 2 KiB fallback
    }

    hipMemsetAsync(ws, 0, (size_t)slots * slotStride * sizeof(float), stream);

    // Persistent grid: 2048 blocks x 4 waves = 8192 waves (32 waves/CU),
    // each wave grid-strides over ~NP/8192 points.
    int blocks = (NP + 3) / 4;
    if (blocks > 2048) blocks = 2048;
    const int totalWaves = blocks * 4;

    sdf_main<<<blocks, 256, 0, stream>>>(points, v, vn, sr, ws, NP, P,
                                         totalWaves, slots, slotStride);
    sdf_reduce<<<1, RED_THREADS, 0, stream>>>(ws, out, N, slots, slotStride);
}